// Round 1
// baseline (160.592 us; speedup 1.0000x reference)
//
#include <hip/hip_runtime.h>
#include <math.h>

#define SEGN 5
#define SEG_LEN 100
#define WLEN 500
#define WSTEP 250
#define ALPHA_C (-0.01f)
#define BLOCK 256

// Per-segment accumulation: xx (self dot), and xy against y-segments i-1, i, i+1.
// HASM/HASP are compile-time 0/1; dead branches eliminated.
#define SEG_BODY(IVAR, HASM, HASP, AXX, AM, A0, AP)                              \
  {                                                                               \
    const float2* xv2 = reinterpret_cast<const float2*>(xp + (IVAR) * SEG_LEN);   \
    _Pragma("unroll 10")                                                          \
    for (int s2 = 0; s2 < SEG_LEN / 2; ++s2) {                                    \
      float2 xv = xv2[s2];                                                        \
      int s = s2 * 2;                                                             \
      float2 y0 = *reinterpret_cast<const float2*>(&sS[(IVAR) * SEG_LEN + s]);    \
      AXX += xv.x * xv.x + xv.y * xv.y;                                           \
      A0  += xv.x * y0.x + xv.y * y0.y;                                           \
      if (HASM) {                                                                 \
        float2 ym = *reinterpret_cast<const float2*>(                             \
            &sS[((IVAR) - 1) * SEG_LEN + s]);                                     \
        AM += xv.x * ym.x + xv.y * ym.y;                                          \
      }                                                                           \
      if (HASP) {                                                                 \
        float2 yp = *reinterpret_cast<const float2*>(                             \
            &sS[((IVAR) + 1) * SEG_LEN + s]);                                     \
        AP += xv.x * yp.x + xv.y * yp.y;                                          \
      }                                                                           \
    }                                                                             \
  }

__global__ __launch_bounds__(BLOCK)
void softmin_dtw_kernel(const float* __restrict__ x, const float* __restrict__ S,
                        float* __restrict__ out, int W, float inv_W) {
  __shared__ __align__(16) float sS[WLEN];
  __shared__ float sYY[SEGN];
  __shared__ float sRed[BLOCK / 64];

  const int tid = threadIdx.x;

  // Stage S into LDS
  for (int t = tid; t < WLEN; t += BLOCK) sS[t] = S[t];
  __syncthreads();
  // yy[j] = sum of squares of S segment j (5 threads, once per block)
  if (tid < SEGN) {
    float acc = 0.f;
    #pragma unroll 4
    for (int s = 0; s < SEG_LEN; ++s) {
      float v = sS[tid * SEG_LEN + s];
      acc += v * v;
    }
    sYY[tid] = acc;
  }
  __syncthreads();

  const int w = blockIdx.x * BLOCK + tid;
  float xi = 0.f;
  if (w < W) {
    const float* xp = x + (long long)w * WSTEP;

    float xx0 = 0.f, xx1 = 0.f, xx2 = 0.f, xx3 = 0.f, xx4 = 0.f;
    float xy00 = 0.f, xy01 = 0.f;
    float xy10 = 0.f, xy11 = 0.f, xy12 = 0.f;
    float xy21 = 0.f, xy22 = 0.f, xy23 = 0.f;
    float xy32 = 0.f, xy33 = 0.f, xy34 = 0.f;
    float xy43 = 0.f, xy44 = 0.f;
    float dummy = 0.f;

    SEG_BODY(0, 0, 1, xx0, dummy, xy00, xy01)
    SEG_BODY(1, 1, 1, xx1, xy10, xy11, xy12)
    SEG_BODY(2, 1, 1, xx2, xy21, xy22, xy23)
    SEG_BODY(3, 1, 1, xx3, xy32, xy33, xy34)
    SEG_BODY(4, 1, 0, xx4, xy43, xy44, dummy)

    // Band cell costs C[i][j] = xx[i] + yy[j] - 2*xy[i][j]
    const float yy0 = sYY[0], yy1 = sYY[1], yy2 = sYY[2], yy3 = sYY[3], yy4 = sYY[4];
    const float C00 = xx0 + yy0 - 2.f * xy00;
    const float C01 = xx0 + yy1 - 2.f * xy01;
    const float C10 = xx1 + yy0 - 2.f * xy10;
    const float C11 = xx1 + yy1 - 2.f * xy11;
    const float C12 = xx1 + yy2 - 2.f * xy12;
    const float C21 = xx2 + yy1 - 2.f * xy21;
    const float C22 = xx2 + yy2 - 2.f * xy22;
    const float C23 = xx2 + yy3 - 2.f * xy23;
    const float C32 = xx3 + yy2 - 2.f * xy32;
    const float C33 = xx3 + yy3 - 2.f * xy33;
    const float C34 = xx3 + yy4 - 2.f * xy34;
    const float C43 = xx4 + yy3 - 2.f * xy43;
    const float C44 = xx4 + yy4 - 2.f * xy44;

    // Banded DTW DP, infinities resolved symbolically.
    // cXY = cum[X][Y] in the reference's (SEG+1)x(SEG+1) cumulative array.
    const float c11 = C00;
    const float c12 = C01 + c11;
    const float c21 = C10 + c11;
    const float c22 = C11 + fminf(fminf(c12, c21), c11);
    const float c23 = C12 + fminf(c22, c12);
    const float c32 = C21 + fminf(c22, c21);
    const float c33 = C22 + fminf(fminf(c23, c32), c22);
    const float c34 = C23 + fminf(c33, c23);
    const float c43 = C32 + fminf(c33, c32);
    const float c44 = C33 + fminf(fminf(c34, c43), c33);
    const float c45 = C34 + fminf(c44, c34);
    const float c54 = C43 + fminf(c44, c43);
    const float c55 = C44 + fminf(fminf(c45, c54), c44);

    xi = expf(ALPHA_C * sqrtf(fmaxf(c55, 0.f)));
  }

  // Block reduction: wave shuffle -> LDS -> one atomic per block
  #pragma unroll
  for (int off = 32; off > 0; off >>= 1) xi += __shfl_down(xi, off);
  if ((tid & 63) == 0) sRed[tid >> 6] = xi;
  __syncthreads();
  if (tid == 0) {
    float bs = 0.f;
    #pragma unroll
    for (int k = 0; k < BLOCK / 64; ++k) bs += sRed[k];
    atomicAdd(out, bs * inv_W);
  }
}

extern "C" void kernel_launch(void* const* d_in, const int* in_sizes, int n_in,
                              void* d_out, int out_size, void* d_ws, size_t ws_size,
                              hipStream_t stream) {
  const float* x = (const float*)d_in[0];
  const float* S = (const float*)d_in[1];
  float* out = (float*)d_out;

  const long long Q = in_sizes[0];
  const int L = in_sizes[1];         // 500
  const int step = L / 2;            // 250
  const long long n = Q - L;
  const int W = (int)((n + step - 1) / step);  // len(arange(0, Q-L, step)) = 79998

  hipMemsetAsync(out, 0, sizeof(float), stream);

  const int blocks = (W + BLOCK - 1) / BLOCK;
  softmin_dtw_kernel<<<blocks, BLOCK, 0, stream>>>(x, S, out, W, 1.0f / (float)W);
}